// Round 6
// baseline (188.840 us; speedup 1.0000x reference)
//
#include <hip/hip_runtime.h>
#include <hip/hip_fp16.h>

typedef _Float16 f16;
typedef __attribute__((ext_vector_type(8))) _Float16 f16x8;
typedef __attribute__((ext_vector_type(2))) _Float16 f16x2;
typedef __attribute__((ext_vector_type(16))) float f32x16;

#define B_SZ 16
#define T_SZ 2048
#define DIN 512
#define DOUT 512
#define N_SZ 512
#define M_SZ (B_SZ * T_SZ)  /* 32768 */
#define NCHUNK 16
#define LCHUNK 128          /* T_SZ / NCHUNK */

__device__ __forceinline__ void gload_lds16(const void* g, void* l) {
  __builtin_amdgcn_global_load_lds(
      (const __attribute__((address_space(1))) void*)g,
      (__attribute__((address_space(3))) void*)l, 16, 0, 0);
}

// ---------------- fused prep kernel (grid-range split) ----------------

__global__ void prep_all(const float* __restrict__ nu_log,
                         const float* __restrict__ theta_log,
                         const float* __restrict__ gamma_log,
                         const float* __restrict__ B_re, const float* __restrict__ B_im,
                         const float* __restrict__ C_re, const float* __restrict__ C_im,
                         const float* __restrict__ Dm, const float* __restrict__ input,
                         float2* __restrict__ lam2, float2* __restrict__ lamL2,
                         f16* __restrict__ W1, f16* __restrict__ W2,
                         f16* __restrict__ A2) {
  int b = blockIdx.x;
  if (b < 2) {
    int n = b * 256 + threadIdx.x;
    float nu = expf(nu_log[n]);
    float ph = expf(theta_log[n]);
    float la = expf(-nu);
    lam2[n] = make_float2(la * cosf(ph), la * sinf(ph));
    float laL = expf(-nu * (float)LCHUNK);
    float phL = ph * (float)LCHUNK;
    lamL2[n] = make_float2(laL * cosf(phL), laL * sinf(phL));
  } else if (b < 2 + 2048) {
    int tid = (b - 2) * 256 + threadIdx.x;   // 1024*512
    int np = tid >> 9;
    int d = tid & 511;
    int n = np >> 1;
    float g = expf(gamma_log[n]);
    const float* src = (np & 1) ? B_im : B_re;
    W1[(size_t)np * 512 + d] = (f16)(src[(size_t)n * 512 + d] * g);
  } else if (b < 2 + 2048 + 3072) {
    int tid = (b - 2050) * 256 + threadIdx.x;  // 512*1536
    int j = tid / 1536;
    int k = tid - j * 1536;
    float v;
    if (k < 512)       v =  C_re[(size_t)j * 512 + k];
    else if (k < 1024) v = -C_im[(size_t)j * 512 + (k - 512)];
    else               v =  Dm[(size_t)j * 512 + (k - 1024)];
    W2[(size_t)j * 1536 + k] = (f16)v;
  } else {
    int tid = (b - 5122) * 256 + threadIdx.x;  // 32768*512/8
    int m = tid >> 6;
    int d0 = (tid & 63) << 3;
    const float4* p = (const float4*)(input + (size_t)m * DIN + d0);
    float4 a = p[0], c = p[1];
    f16x8 h;
    h[0] = (f16)a.x; h[1] = (f16)a.y; h[2] = (f16)a.z; h[3] = (f16)a.w;
    h[4] = (f16)c.x; h[5] = (f16)c.y; h[6] = (f16)c.z; h[7] = (f16)c.w;
    *(f16x8*)(A2 + (size_t)m * 1536 + 1024 + d0) = h;
  }
}

// ---------------- scan (3 phases, fp32 math, f16 Bu) ----------------

__global__ void scan_a(const f16* __restrict__ Bu, const float2* __restrict__ lam2,
                       float2* __restrict__ S) {
  int tid = blockIdx.x * 256 + threadIdx.x;  // B*NCHUNK*N = 131072
  int n = tid & 511;
  int c = (tid >> 9) & (NCHUNK - 1);
  int b = tid >> 13;
  float2 l = lam2[n];
  const unsigned* bu = (const unsigned*)Bu + (size_t)(b * T_SZ + c * LCHUNK) * 512 + n;
  float sre = 0.f, sim = 0.f;
#pragma unroll 8
  for (int t = 0; t < LCHUNK; ++t) {
    unsigned u = bu[(size_t)t * 512];
    f16x2 h = __builtin_bit_cast(f16x2, u);
    float nre = l.x * sre - l.y * sim + (float)h.x;
    sim = l.x * sim + l.y * sre + (float)h.y;
    sre = nre;
  }
  S[(size_t)(b * NCHUNK + c) * 512 + n] = make_float2(sre, sim);
}

__global__ void scan_b(const float2* __restrict__ S, const float2* __restrict__ lamL2,
                       float2* __restrict__ Carry) {
  int tid = blockIdx.x * 256 + threadIdx.x;  // 8192
  int n = tid & 511;
  int b = tid >> 9;
  float2 lL = lamL2[n];
  float cre = 0.f, cim = 0.f;
  for (int c = 0; c < NCHUNK; ++c) {
    size_t idx = (size_t)(b * NCHUNK + c) * 512 + n;
    Carry[idx] = make_float2(cre, cim);
    float2 s = S[idx];
    float nre = lL.x * cre - lL.y * cim + s.x;
    cim = lL.x * cim + lL.y * cre + s.y;
    cre = nre;
  }
}

__global__ void scan_c(const f16* __restrict__ Bu, const float2* __restrict__ lam2,
                       const float2* __restrict__ Carry, f16* __restrict__ A2) {
  int tid = blockIdx.x * 256 + threadIdx.x;
  int n = tid & 511;
  int c = (tid >> 9) & (NCHUNK - 1);
  int b = tid >> 13;
  float2 l = lam2[n];
  float2 car = Carry[(size_t)(b * NCHUNK + c) * 512 + n];
  float sre = car.x, sim = car.y;
  int m0 = b * T_SZ + c * LCHUNK;
  const unsigned* bu = (const unsigned*)Bu + (size_t)m0 * 512 + n;
  f16* outre = A2 + (size_t)m0 * 1536 + n;
#pragma unroll 4
  for (int t = 0; t < LCHUNK; ++t) {
    unsigned u = bu[(size_t)t * 512];
    f16x2 h = __builtin_bit_cast(f16x2, u);
    float nre = l.x * sre - l.y * sim + (float)h.x;
    sim = l.x * sim + l.y * sre + (float)h.y;
    sre = nre;
    outre[(size_t)t * 1536] = (f16)sre;
    outre[(size_t)t * 1536 + 512] = (f16)sim;
  }
}

// ---------------- 256x128 8-wave ring-4 GEMM, issue-early/drain-late ------------
// Granule = K=32 slice: A 256x32 + B 128x32 = 24 KB; ring-4 = 96 KiB LDS.
// 8 waves, per-wave output 64x64 (wr=wid>>1 M-band, wc=wid&1 N-half).
// Phase g: [issue 8 ds_reads for g+1 -> alternate frag set][stage(g+3): 3 gloads]
//          [lgkmcnt(8): g's frags ready, g+1's 8 stay in flight]
//          [8 MFMA on g's set -- LDS pipe chews g+1's reads DURING the cluster]
//          [vmcnt(3): g+2 landed][barrier]. Counted waits never 0 mid-loop.
// Swizzle: same measured-zero-conflict geometry as R3/R4 (key=(r&3)^((r>>2)&3)).
// C/D layout (32x32): col=lane&31, row=(r&3)+8*(r>>2)+4*(lane>>5)  [m74/m101].

template <typename CT>
__global__ __launch_bounds__(512, 2) void gemm_pipe(
    const f16* __restrict__ A, int lda,
    const f16* __restrict__ Bm, int ldb,
    CT* __restrict__ C, int ldc, int K, int nxt) {
  extern __shared__ f16 smem[];  // slot s (12288 halfs): A [0,8192), B [8192,12288)
  const int tid = threadIdx.x;
  const int lane = tid & 63;
  const int wid = tid >> 6;
  const int wr = wid >> 1;        // 0..3  (64-row band)
  const int wc = wid & 1;         // 0..1  (64-col half)
  const int r32 = lane & 31;
  const int khalf = lane >> 5;    // 0..1
  const int key = (r32 & 3) ^ ((r32 >> 2) & 3);

  const int nwg = gridDim.x;
  const int id = blockIdx.x;
  const int swz = (id & 7) * (nwg >> 3) + (id >> 3);
  const int m0 = (swz / nxt) * 256;
  const int n0 = (swz % nxt) * 128;

  const int srow = tid >> 2;                               // 0..127
  const int scol = ((tid & 3) ^ (srow & 3) ^ ((srow >> 2) & 3)) * 8;
  const int NG = K >> 5;

  f32x16 acc[2][2];
#pragma unroll
  for (int i = 0; i < 2; ++i)
#pragma unroll
    for (int j = 0; j < 2; ++j)
#pragma unroll
      for (int r = 0; r < 16; ++r) acc[i][j][r] = 0.f;

  auto stage = [&](int g) {
    f16* dst = smem + (g & 3) * 12288 + tid * 8;
    const f16* gA = A + (size_t)(m0 + srow) * lda + g * 32 + scol;
    const f16* gB = Bm + (size_t)(n0 + srow) * ldb + g * 32 + scol;
    gload_lds16(gA, dst);                                // A rows [0,128)
    gload_lds16(gA + (size_t)128 * lda, dst + 4096);     // A rows [128,256)
    gload_lds16(gB, dst + 8192);                         // B rows [0,128)
  };

  auto ldfrags = [&](int g, f16x8 (&af)[2][2], f16x8 (&bf)[2][2]) {
    const f16* sa = smem + (g & 3) * 12288 + (wr * 64) * 32;
    const f16* sb = smem + (g & 3) * 12288 + 8192 + (wc * 64) * 32;
#pragma unroll
    for (int mi = 0; mi < 2; ++mi)
#pragma unroll
      for (int k = 0; k < 2; ++k)
        af[mi][k] = *(const f16x8*)(sa + (mi * 32 + r32) * 32 +
                                    (((k * 2 + khalf) ^ key) * 8));
#pragma unroll
    for (int ni = 0; ni < 2; ++ni)
#pragma unroll
      for (int k = 0; k < 2; ++k)
        bf[ni][k] = *(const f16x8*)(sb + (ni * 32 + r32) * 32 +
                                    (((k * 2 + khalf) ^ key) * 8));
  };

  f16x8 afA[2][2], bfA[2][2], afB[2][2], bfB[2][2];

  auto body = [&](int g, f16x8 (&uaf)[2][2], f16x8 (&ubf)[2][2],
                  f16x8 (&naf)[2][2], f16x8 (&nbf)[2][2]) {
    if (g + 1 < NG) ldfrags(g + 1, naf, nbf);   // issue 8 ds_reads (next set)
    if (g + 3 < NG) stage(g + 3);               // issue 3 gloads
    __builtin_amdgcn_sched_barrier(0);
    if (g + 1 < NG)
      asm volatile("s_waitcnt lgkmcnt(8)" ::: "memory");  // g's frags ready
    else
      asm volatile("s_waitcnt lgkmcnt(0)" ::: "memory");
    __builtin_amdgcn_sched_barrier(0);
    __builtin_amdgcn_s_setprio(1);
#pragma unroll
    for (int k = 0; k < 2; ++k)
#pragma unroll
      for (int mi = 0; mi < 2; ++mi)
#pragma unroll
        for (int ni = 0; ni < 2; ++ni)
          acc[mi][ni] = __builtin_amdgcn_mfma_f32_32x32x16_f16(
              uaf[mi][k], ubf[ni][k], acc[mi][ni], 0, 0, 0);
    __builtin_amdgcn_s_setprio(0);
    __builtin_amdgcn_sched_barrier(0);
    if (g + 3 < NG)
      asm volatile("s_waitcnt vmcnt(3)" ::: "memory");    // g+2 landed
    else if (g + 2 < NG)
      asm volatile("s_waitcnt vmcnt(0)" ::: "memory");
    __builtin_amdgcn_s_barrier();
    __builtin_amdgcn_sched_barrier(0);
  };

  // prologue: stage g0..g2 (9 loads), confirm g0,g1, collectivize, preload frags(0)
  stage(0);
  stage(1);
  stage(2);
  asm volatile("s_waitcnt vmcnt(3)" ::: "memory");
  __builtin_amdgcn_sched_barrier(0);
  __builtin_amdgcn_s_barrier();
  __builtin_amdgcn_sched_barrier(0);
  ldfrags(0, afA, bfA);

  for (int g = 0; g < NG; g += 2) {
    body(g, afA, bfA, afB, bfB);
    body(g + 1, afB, bfB, afA, bfA);
  }

#pragma unroll
  for (int mi = 0; mi < 2; ++mi)
#pragma unroll
    for (int ni = 0; ni < 2; ++ni)
#pragma unroll
      for (int r = 0; r < 16; ++r) {
        int row = m0 + wr * 64 + mi * 32 + (r & 3) + ((r >> 2) * 8) + khalf * 4;
        int col = n0 + wc * 64 + ni * 32 + r32;
        C[(size_t)row * ldc + col] = (CT)acc[mi][ni][r];
      }
}

// ---------------- launch ----------------

extern "C" void kernel_launch(void* const* d_in, const int* in_sizes, int n_in,
                              void* d_out, int out_size, void* d_ws, size_t ws_size,
                              hipStream_t stream) {
  const float* input = (const float*)d_in[0];
  const float* Dmat = (const float*)d_in[1];
  const float* nu_log = (const float*)d_in[2];
  const float* theta_log = (const float*)d_in[3];
  const float* gamma_log = (const float*)d_in[4];
  const float* B_re = (const float*)d_in[5];
  const float* B_im = (const float*)d_in[6];
  const float* C_re = (const float*)d_in[7];
  const float* C_im = (const float*)d_in[8];
  float* y = (float*)d_out;

  char* ws = (char*)d_ws;
  size_t off = 0;
  auto alloc = [&](size_t bytes) {
    void* p = ws + off;
    off = (off + bytes + 255) & ~(size_t)255;
    return p;
  };
  float2* lam2 = (float2*)alloc(N_SZ * sizeof(float2));
  float2* lamL2 = (float2*)alloc(N_SZ * sizeof(float2));
  f16* W1 = (f16*)alloc((size_t)2 * N_SZ * DIN * 2);        // [1024][512] f16
  f16* W2 = (f16*)alloc((size_t)DOUT * 1536 * 2);           // [512][1536] f16
  f16* A2 = (f16*)alloc((size_t)M_SZ * 1536 * 2);           // [M][re|im|in] f16
  f16* Bu = (f16*)alloc((size_t)M_SZ * 2 * N_SZ * 2);       // [M][1024] f16 (re,im)
  float2* S = (float2*)alloc((size_t)B_SZ * NCHUNK * N_SZ * sizeof(float2));
  float2* Carry = (float2*)alloc((size_t)B_SZ * NCHUNK * N_SZ * sizeof(float2));

  const int shmem = 98304;  // 4 slots x 24 KiB
  {
    auto* g16 = gemm_pipe<f16>;
    auto* g32 = gemm_pipe<float>;
    hipFuncSetAttribute((const void*)g16,
                        hipFuncAttributeMaxDynamicSharedMemorySize, shmem);
    hipFuncSetAttribute((const void*)g32,
                        hipFuncAttributeMaxDynamicSharedMemorySize, shmem);
  }

  prep_all<<<13314, 256, 0, stream>>>(nu_log, theta_log, gamma_log, B_re, B_im,
                                      C_re, C_im, Dmat, input, lam2, lamL2, W1, W2, A2);

  // Bu = input_f16 @ W1^T   (A = A2 cols [1024,1536), lda=1536); 128x8=1024 blocks
  gemm_pipe<f16><<<1024, 512, shmem, stream>>>(A2 + 1024, 1536, W1, 512, Bu, 1024, 512, 8);

  scan_a<<<(B_SZ * NCHUNK * N_SZ) / 256, 256, 0, stream>>>(Bu, lam2, S);
  scan_b<<<(B_SZ * N_SZ) / 256, 256, 0, stream>>>(S, lamL2, Carry);
  scan_c<<<(B_SZ * NCHUNK * N_SZ) / 256, 256, 0, stream>>>(Bu, lam2, Carry, A2);

  // y = [s_re | s_im | in] @ [C_re | -C_im | D]^T ; 128x4=512 blocks
  gemm_pipe<float><<<512, 512, shmem, stream>>>(A2, 1536, W2, 1536, y, 512, 1536, 4);
}

// Round 7
// 154.327 us; speedup vs baseline: 1.2236x; 1.2236x over previous
//
#include <hip/hip_runtime.h>
#include <hip/hip_fp16.h>

typedef _Float16 f16;
typedef __attribute__((ext_vector_type(8))) _Float16 f16x8;
typedef __attribute__((ext_vector_type(4))) _Float16 f16x4;
typedef __attribute__((ext_vector_type(2))) _Float16 f16x2;
typedef __attribute__((ext_vector_type(4))) float f32x4;

#define B_SZ 16
#define T_SZ 2048
#define DIN 512
#define DOUT 512
#define N_SZ 512
#define M_SZ (B_SZ * T_SZ)  /* 32768 */
#define LCHUNK 64
#define NCHUNK 32           /* T_SZ / LCHUNK */

__device__ __forceinline__ void gload_lds16(const void* g, void* l) {
  __builtin_amdgcn_global_load_lds(
      (const __attribute__((address_space(1))) void*)g,
      (__attribute__((address_space(3))) void*)l, 16, 0, 0);
}

// ---------------- fused prep kernel (grid-range split) ----------------
// [0,2): lam + lam^64 ; [2,4): lamp table lam^(j+1) [64][512]
// [4,2052): W1 ; [2052,5124): W2 ; [5124,13316): input->f16

__global__ void prep_all(const float* __restrict__ nu_log,
                         const float* __restrict__ theta_log,
                         const float* __restrict__ gamma_log,
                         const float* __restrict__ B_re, const float* __restrict__ B_im,
                         const float* __restrict__ C_re, const float* __restrict__ C_im,
                         const float* __restrict__ Dm, const float* __restrict__ input,
                         float2* __restrict__ lam2, float2* __restrict__ lamL2,
                         float2* __restrict__ lamp,
                         f16* __restrict__ W1, f16* __restrict__ W2,
                         f16* __restrict__ A2) {
  int b = blockIdx.x;
  if (b < 2) {
    int n = b * 256 + threadIdx.x;
    float nu = expf(nu_log[n]);
    float ph = expf(theta_log[n]);
    float la = expf(-nu);
    lam2[n] = make_float2(la * cosf(ph), la * sinf(ph));
    float laL = expf(-nu * (float)LCHUNK);
    float phL = ph * (float)LCHUNK;
    lamL2[n] = make_float2(laL * cosf(phL), laL * sinf(phL));
  } else if (b < 4) {
    int n = (b - 2) * 256 + threadIdx.x;
    float nu = expf(nu_log[n]);
    float ph = expf(theta_log[n]);
    float la = expf(-nu);
    float2 l1 = make_float2(la * cosf(ph), la * sinf(ph));
    float2 cur = l1;
    for (int j = 0; j < LCHUNK; ++j) {
      lamp[(size_t)j * 512 + n] = cur;   // lam^(j+1)
      float nre = cur.x * l1.x - cur.y * l1.y;
      cur.y = cur.x * l1.y + cur.y * l1.x;
      cur.x = nre;
    }
  } else if (b < 4 + 2048) {
    int tid = (b - 4) * 256 + threadIdx.x;   // 1024*512
    int np = tid >> 9;
    int d = tid & 511;
    int n = np >> 1;
    float g = expf(gamma_log[n]);
    const float* src = (np & 1) ? B_im : B_re;
    W1[(size_t)np * 512 + d] = (f16)(src[(size_t)n * 512 + d] * g);
  } else if (b < 4 + 2048 + 3072) {
    int tid = (b - 2052) * 256 + threadIdx.x;  // 512*1536
    int j = tid / 1536;
    int k = tid - j * 1536;
    float v;
    if (k < 512)       v =  C_re[(size_t)j * 512 + k];
    else if (k < 1024) v = -C_im[(size_t)j * 512 + (k - 512)];
    else               v =  Dm[(size_t)j * 512 + (k - 1024)];
    W2[(size_t)j * 1536 + k] = (f16)v;
  } else {
    int tid = (b - 5124) * 256 + threadIdx.x;  // 32768*512/8
    int m = tid >> 6;
    int d0 = (tid & 63) << 3;
    const float4* p = (const float4*)(input + (size_t)m * DIN + d0);
    float4 a = p[0], c = p[1];
    f16x8 h;
    h[0] = (f16)a.x; h[1] = (f16)a.y; h[2] = (f16)a.z; h[3] = (f16)a.w;
    h[4] = (f16)c.x; h[5] = (f16)c.y; h[6] = (f16)c.z; h[7] = (f16)c.w;
    *(f16x8*)(A2 + (size_t)m * 1536 + 1024 + d0) = h;
  }
}

// ---------------- chunk-carry scan + parallel carry application ----------------

__global__ void scan_b(const float2* __restrict__ S, const float2* __restrict__ lamL2,
                       float2* __restrict__ Carry) {
  int tid = blockIdx.x * 256 + threadIdx.x;  // 8192
  int n = tid & 511;
  int b = tid >> 9;
  float2 lL = lamL2[n];
  float cre = 0.f, cim = 0.f;
  for (int c = 0; c < NCHUNK; ++c) {
    size_t idx = (size_t)(b * NCHUNK + c) * 512 + n;
    Carry[idx] = make_float2(cre, cim);
    float2 s = S[idx];
    float nre = lL.x * cre - lL.y * cim + s.x;
    cim = lL.x * cim + lL.y * cre + s.y;
    cre = nre;
  }
}

// states[m][n] = sloc[m][n] + lam^(j+1)*carry ; j = m & 63. Fully parallel.
__global__ void apply_carry(const unsigned* __restrict__ sloc,
                            const float2* __restrict__ lamp,
                            const float2* __restrict__ Carry,
                            f16* __restrict__ A2) {
  int tid = blockIdx.x * 256 + threadIdx.x;   // M * 128
  int g = tid & 127;            // 4-n group
  int m = tid >> 7;
  int j = m & 63;
  int bc = m >> 6;              // b*NCHUNK + chunk
  int n0 = g * 4;
  const float2* lpp = lamp + (size_t)j * 512 + n0;
  const float2* crp = Carry + (size_t)bc * 512 + n0;
  uint4 sv = *(const uint4*)(sloc + (size_t)m * 512 + n0);
  unsigned u4[4] = {sv.x, sv.y, sv.z, sv.w};
  f16x4 ore, oim;
#pragma unroll
  for (int q = 0; q < 4; ++q) {
    f16x2 u = __builtin_bit_cast(f16x2, u4[q]);
    float2 lp = lpp[q];
    float2 cr = crp[q];
    ore[q] = (f16)((float)u.x + lp.x * cr.x - lp.y * cr.y);
    oim[q] = (f16)((float)u.y + lp.x * cr.y + lp.y * cr.x);
  }
  *(f16x4*)(A2 + (size_t)m * 1536 + n0) = ore;
  *(f16x4*)(A2 + (size_t)m * 1536 + 512 + n0) = oim;
}

// ---------------- 256x256 8-wave MFMA GEMM (R1 structure, measured best) --------
// BK=64, 2 LDS buffers, 4 phases/K-tile of 16 MFMA, setprio, counted-in-flight
// staging. FUSE=true: instead of writing C, run the per-wave local complex scan
// (chunk L=64 aligned to wave subtiles) and emit sloc (f16x2) + chunk-end S.

template <typename CT, bool FUSE>
__global__ __launch_bounds__(512, 2) void gemm256(
    const f16* __restrict__ A, int lda,
    const f16* __restrict__ Bm, int ldb,
    CT* __restrict__ C, int ldc, int K, int nxt,
    const float2* __restrict__ lam2, unsigned* __restrict__ sloc,
    float2* __restrict__ Svec) {
  extern __shared__ f16 smem[];
  f16* sA = smem;                 // 2 bufs x 256x64 halfs
  f16* sB = smem + 2 * 16384;

  const int tid = threadIdx.x;
  const int lane = tid & 63;
  const int wid = tid >> 6;
  const int wr = wid >> 2;        // 0..1
  const int wc = wid & 3;         // 0..3
  const int fr = lane & 15;
  const int fg = lane >> 4;       // 0..3
  const int xr = fr & 7;

  const int nwg = gridDim.x;
  const int id = blockIdx.x;
  const int swz = (id & 7) * (nwg >> 3) + (id >> 3);
  const int m0 = (swz / nxt) * 256;
  const int n0 = (swz % nxt) * 256;

  const int srow = tid >> 3;
  const int scol = ((tid & 7) ^ (srow & 7)) * 8;
  const int sdst = wid * 512;

  const int NT = K >> 6;

  f32x4 acc[8][4];
#pragma unroll
  for (int i = 0; i < 8; ++i)
#pragma unroll
    for (int j = 0; j < 4; ++j) acc[i][j] = f32x4{0.f, 0.f, 0.f, 0.f};

  const int ar0 = wr * 128;
  const int bc0 = wc * 64;

  auto stage = [&](int t) {
    const int b = t & 1;
    f16* dA = sA + b * 16384 + sdst;
    f16* dB = sB + b * 16384 + sdst;
    const f16* gA = A + (size_t)(m0 + srow) * lda + t * 64 + scol;
    const f16* gB = Bm + (size_t)(n0 + srow) * ldb + t * 64 + scol;
    gload_lds16(gA, dA);
    gload_lds16(gA + (size_t)64 * lda, dA + 4096);
    gload_lds16(gA + (size_t)128 * lda, dA + 8192);
    gload_lds16(gA + (size_t)192 * lda, dA + 12288);
    gload_lds16(gB, dB);
    gload_lds16(gB + (size_t)64 * ldb, dB + 4096);
    gload_lds16(gB + (size_t)128 * ldb, dB + 8192);
    gload_lds16(gB + (size_t)192 * ldb, dB + 12288);
  };

  auto barrier = [&]() {
    __builtin_amdgcn_sched_barrier(0);
    __builtin_amdgcn_s_barrier();
    __builtin_amdgcn_sched_barrier(0);
  };

  stage(0);
  asm volatile("s_waitcnt vmcnt(0)" ::: "memory");
  barrier();

  f16x8 bf[4][2];
  for (int t = 0; t < NT; ++t) {
    const int b = t & 1;
    const f16* bA = sA + b * 16384;
    const f16* bB = sB + b * 16384;
    if (t + 1 < NT) stage(t + 1);
#pragma unroll
    for (int h = 0; h < 4; ++h) {
      if (h == 0) {
#pragma unroll
        for (int nrep = 0; nrep < 4; ++nrep)
#pragma unroll
          for (int ks = 0; ks < 2; ++ks) {
            int row = bc0 + nrep * 16 + fr;
            bf[nrep][ks] =
                *(const f16x8*)(bB + row * 64 + (((ks * 4 + fg) ^ xr) * 8));
          }
      }
      f16x8 af[2][2];
#pragma unroll
      for (int mi = 0; mi < 2; ++mi)
#pragma unroll
        for (int ks = 0; ks < 2; ++ks) {
          int row = ar0 + (h * 2 + mi) * 16 + fr;
          af[mi][ks] =
              *(const f16x8*)(bA + row * 64 + (((ks * 4 + fg) ^ xr) * 8));
        }
      __builtin_amdgcn_s_setprio(1);
#pragma unroll
      for (int mi = 0; mi < 2; ++mi)
#pragma unroll
        for (int nrep = 0; nrep < 4; ++nrep)
#pragma unroll
          for (int ks = 0; ks < 2; ++ks)
            acc[h * 2 + mi][nrep] = __builtin_amdgcn_mfma_f32_16x16x32_f16(
                af[mi][ks], bf[nrep][ks], acc[h * 2 + mi][nrep], 0, 0, 0);
      __builtin_amdgcn_s_setprio(0);
      if (h == 3 && t + 1 < NT)
        asm volatile("s_waitcnt vmcnt(0)" ::: "memory");
      barrier();
    }
  }

  if constexpr (FUSE) {
    // ---- fused local scan epilogue ----
    // acc -> per-wave LDS tile [128][64] f16 (smem fully free after final barrier)
    f16* reg = smem + wid * 8192;
#pragma unroll
    for (int mi = 0; mi < 8; ++mi)
#pragma unroll
      for (int ni = 0; ni < 4; ++ni)
#pragma unroll
        for (int r = 0; r < 4; ++r)
          reg[(mi * 16 + fg * 4 + r) * 64 + ni * 16 + fr] = (f16)acc[mi][ni][r];
    __syncthreads();
    // lane l: half=l>>5 picks chunk (rows half*64..+64), nc=l&31 picks n-pair
    const int half = lane >> 5;
    const int nc = lane & 31;
    const int n = ((n0 + wc * 64) >> 1) + nc;
    const float2 l2 = lam2[n];
    const f16* col = smem + wid * 8192 + (half * 64) * 64 + 2 * nc;
    const int mbase = m0 + wr * 128 + half * 64;
    unsigned* sp = sloc + (size_t)mbase * 512 + n;
    float sre = 0.f, sim = 0.f;
#pragma unroll 1
    for (int j0 = 0; j0 < 64; j0 += 8) {
      f16x2 u[8];
#pragma unroll
      for (int q = 0; q < 8; ++q) u[q] = *(const f16x2*)(col + (j0 + q) * 64);
#pragma unroll
      for (int q = 0; q < 8; ++q) {
        float nre = l2.x * sre - l2.y * sim + (float)u[q].x;
        sim = l2.x * sim + l2.y * sre + (float)u[q].y;
        sre = nre;
        f16x2 o;
        o.x = (f16)sre;
        o.y = (f16)sim;
        sp[(size_t)(j0 + q) * 512] = __builtin_bit_cast(unsigned, o);
      }
    }
    Svec[(size_t)((m0 >> 11) * NCHUNK + ((mbase >> 6) & (NCHUNK - 1))) * 512 + n] =
        make_float2(sre, sim);
  } else {
#pragma unroll
    for (int mi = 0; mi < 8; ++mi) {
      int rbase = m0 + ar0 + mi * 16 + fg * 4;
#pragma unroll
      for (int ni = 0; ni < 4; ++ni) {
        int col = n0 + bc0 + ni * 16 + fr;
#pragma unroll
        for (int r = 0; r < 4; ++r)
          C[(size_t)(rbase + r) * ldc + col] = (CT)acc[mi][ni][r];
      }
    }
  }
}

// ---------------- launch ----------------

extern "C" void kernel_launch(void* const* d_in, const int* in_sizes, int n_in,
                              void* d_out, int out_size, void* d_ws, size_t ws_size,
                              hipStream_t stream) {
  const float* input = (const float*)d_in[0];
  const float* Dmat = (const float*)d_in[1];
  const float* nu_log = (const float*)d_in[2];
  const float* theta_log = (const float*)d_in[3];
  const float* gamma_log = (const float*)d_in[4];
  const float* B_re = (const float*)d_in[5];
  const float* B_im = (const float*)d_in[6];
  const float* C_re = (const float*)d_in[7];
  const float* C_im = (const float*)d_in[8];
  float* y = (float*)d_out;

  char* ws = (char*)d_ws;
  size_t off = 0;
  auto alloc = [&](size_t bytes) {
    void* p = ws + off;
    off = (off + bytes + 255) & ~(size_t)255;
    return p;
  };
  float2* lam2 = (float2*)alloc(N_SZ * sizeof(float2));
  float2* lamL2 = (float2*)alloc(N_SZ * sizeof(float2));
  float2* lamp = (float2*)alloc((size_t)LCHUNK * N_SZ * sizeof(float2));  // 256KB
  f16* W1 = (f16*)alloc((size_t)2 * N_SZ * DIN * 2);        // [1024][512] f16
  f16* W2 = (f16*)alloc((size_t)DOUT * 1536 * 2);           // [512][1536] f16
  f16* A2 = (f16*)alloc((size_t)M_SZ * 1536 * 2);           // [M][re|im|in] f16
  unsigned* sloc = (unsigned*)alloc((size_t)M_SZ * N_SZ * 4);  // [M][512] f16x2
  float2* S = (float2*)alloc((size_t)B_SZ * NCHUNK * N_SZ * sizeof(float2));
  float2* Carry = (float2*)alloc((size_t)B_SZ * NCHUNK * N_SZ * sizeof(float2));

  const int shmem = 131072;
  {
    auto* g1 = gemm256<f16, true>;
    auto* g2 = gemm256<float, false>;
    hipFuncSetAttribute((const void*)g1,
                        hipFuncAttributeMaxDynamicSharedMemorySize, shmem);
    hipFuncSetAttribute((const void*)g2,
                        hipFuncAttributeMaxDynamicSharedMemorySize, shmem);
  }

  prep_all<<<13316, 256, 0, stream>>>(nu_log, theta_log, gamma_log, B_re, B_im,
                                      C_re, C_im, Dmat, input, lam2, lamL2, lamp,
                                      W1, W2, A2);

  // GEMM1 + fused local scan: Bu tile computed in-register -> sloc, S
  gemm256<f16, true><<<512, 512, shmem, stream>>>(
      A2 + 1024, 1536, W1, 512, (f16*)nullptr, 0, 512, 4, lam2, sloc, S);

  scan_b<<<(B_SZ * N_SZ) / 256, 256, 0, stream>>>(S, lamL2, Carry);

  apply_carry<<<(M_SZ * 128) / 256, 256, 0, stream>>>(sloc, lamp, Carry, A2);

  // y = [s_re | s_im | in] @ [C_re | -C_im | D]^T
  gemm256<float, false><<<256, 512, shmem, stream>>>(
      A2, 1536, W2, 1536, y, 512, 1536, 2, nullptr, nullptr, nullptr);
}

// Round 8
// 141.828 us; speedup vs baseline: 1.3315x; 1.0881x over previous
//
#include <hip/hip_runtime.h>
#include <hip/hip_fp16.h>

typedef _Float16 f16;
typedef __attribute__((ext_vector_type(8))) _Float16 f16x8;
typedef __attribute__((ext_vector_type(2))) _Float16 f16x2;
typedef __attribute__((ext_vector_type(4))) float f32x4;

#define B_SZ 16
#define T_SZ 2048
#define DIN 512
#define DOUT 512
#define N_SZ 512
#define M_SZ (B_SZ * T_SZ)  /* 32768 */
#define LCHUNK 64
#define NCHUNK 32           /* T_SZ / LCHUNK */

__device__ __forceinline__ void gload_lds16(const void* g, void* l) {
  __builtin_amdgcn_global_load_lds(
      (const __attribute__((address_space(1))) void*)g,
      (__attribute__((address_space(3))) void*)l, 16, 0, 0);
}

// ---------------- fused prep kernel (grid-range split) ----------------
// [0,2): lam + lam^64 ; [2,4): lamp lam^(j+1) [64][512]
// [4,2052): W1 ; [2052,5124): W2 (k<1024 re/im INTERLEAVED) ; rest: input->f16

__global__ void prep_all(const float* __restrict__ nu_log,
                         const float* __restrict__ theta_log,
                         const float* __restrict__ gamma_log,
                         const float* __restrict__ B_re, const float* __restrict__ B_im,
                         const float* __restrict__ C_re, const float* __restrict__ C_im,
                         const float* __restrict__ Dm, const float* __restrict__ input,
                         float2* __restrict__ lam2, float2* __restrict__ lamL2,
                         float2* __restrict__ lamp,
                         f16* __restrict__ W1, f16* __restrict__ W2,
                         f16* __restrict__ inp16) {
  int b = blockIdx.x;
  if (b < 2) {
    int n = b * 256 + threadIdx.x;
    float nu = expf(nu_log[n]);
    float ph = expf(theta_log[n]);
    float la = expf(-nu);
    lam2[n] = make_float2(la * cosf(ph), la * sinf(ph));
    float laL = expf(-nu * (float)LCHUNK);
    float phL = ph * (float)LCHUNK;
    lamL2[n] = make_float2(laL * cosf(phL), laL * sinf(phL));
  } else if (b < 4) {
    int n = (b - 2) * 256 + threadIdx.x;
    float nu = expf(nu_log[n]);
    float ph = expf(theta_log[n]);
    float la = expf(-nu);
    float2 l1 = make_float2(la * cosf(ph), la * sinf(ph));
    float2 cur = l1;
    for (int j = 0; j < LCHUNK; ++j) {
      lamp[(size_t)j * 512 + n] = cur;   // lam^(j+1)
      float nre = cur.x * l1.x - cur.y * l1.y;
      cur.y = cur.x * l1.y + cur.y * l1.x;
      cur.x = nre;
    }
  } else if (b < 4 + 2048) {
    int tid = (b - 4) * 256 + threadIdx.x;   // 1024*512
    int np = tid >> 9;
    int d = tid & 511;
    int n = np >> 1;
    float g = expf(gamma_log[n]);
    const float* src = (np & 1) ? B_im : B_re;
    W1[(size_t)np * 512 + d] = (f16)(src[(size_t)n * 512 + d] * g);
  } else if (b < 4 + 2048 + 3072) {
    int tid = (b - 2052) * 256 + threadIdx.x;  // 512*1536
    int j = tid / 1536;
    int k = tid - j * 1536;
    float v;
    if (k < 1024) {
      int n = k >> 1;
      v = (k & 1) ? -C_im[(size_t)j * 512 + n] : C_re[(size_t)j * 512 + n];
    } else {
      v = Dm[(size_t)j * 512 + (k - 1024)];
    }
    W2[(size_t)j * 1536 + k] = (f16)v;
  } else {
    int tid = (b - 5124) * 256 + threadIdx.x;  // 32768*512/8
    int m = tid >> 6;
    int d0 = (tid & 63) << 3;
    const float4* p = (const float4*)(input + (size_t)m * DIN + d0);
    float4 a = p[0], c = p[1];
    f16x8 h;
    h[0] = (f16)a.x; h[1] = (f16)a.y; h[2] = (f16)a.z; h[3] = (f16)a.w;
    h[4] = (f16)c.x; h[5] = (f16)c.y; h[6] = (f16)c.z; h[7] = (f16)c.w;
    *(f16x8*)(inp16 + (size_t)m * 512 + d0) = h;
  }
}

// ---------------- chunk-carry scan ----------------

__global__ void scan_b(const float2* __restrict__ S, const float2* __restrict__ lamL2,
                       float2* __restrict__ Carry) {
  int tid = blockIdx.x * 256 + threadIdx.x;  // 8192
  int n = tid & 511;
  int b = tid >> 9;
  float2 lL = lamL2[n];
  float cre = 0.f, cim = 0.f;
  for (int c = 0; c < NCHUNK; ++c) {
    size_t idx = (size_t)(b * NCHUNK + c) * 512 + n;
    Carry[idx] = make_float2(cre, cim);
    float2 s = S[idx];
    float nre = lL.x * cre - lL.y * cim + s.x;
    cim = lL.x * cim + lL.y * cre + s.y;
    cre = nre;
  }
}

// ---------------- 256x256 8-wave MFMA GEMM (R1 structure, measured best) --------
// FUSE: GEMM1 epilogue runs the local complex scan (L=64 chunks) -> sloc + S.
// CARRY: readout GEMM; A K-tiles 0..15 are reg-staged from sloc with the chunk
// carry applied in-flight (states = sloc + lam^(j+1)*carry), written to the SAME
// swizzled LDS slots gload_lds would fill; tiles 16..23 (input) + all B via
// gload_lds. W2 k-axis is re/im-interleaved to match sloc's packed layout.

template <typename CT, bool FUSE, bool CARRY>
__global__ __launch_bounds__(512, 2) void gemm256(
    const f16* __restrict__ A, int lda,
    const f16* __restrict__ Bm, int ldb,
    CT* __restrict__ C, int ldc, int K, int nxt,
    const float2* __restrict__ lam2, unsigned* __restrict__ sloc_out,
    float2* __restrict__ Svec,
    const unsigned* __restrict__ sloc_in, const float2* __restrict__ lamp,
    const float2* __restrict__ Carry) {
  extern __shared__ f16 smem[];
  f16* sA = smem;                 // 2 bufs x 256x64 halfs
  f16* sB = smem + 2 * 16384;

  const int tid = threadIdx.x;
  const int lane = tid & 63;
  const int wid = tid >> 6;
  const int wr = wid >> 2;        // 0..1
  const int wc = wid & 3;         // 0..3
  const int fr = lane & 15;
  const int fg = lane >> 4;       // 0..3
  const int xr = fr & 7;

  const int nwg = gridDim.x;
  const int id = blockIdx.x;
  const int swz = (id & 7) * (nwg >> 3) + (id >> 3);
  const int m0 = (swz / nxt) * 256;
  const int n0 = (swz % nxt) * 256;

  const int srow = tid >> 3;                      // 0..63
  const int scol = ((tid & 7) ^ (srow & 7)) * 8;  // swizzled 8-half column
  const int sdst = wid * 512;

  const int NT = K >> 6;

  f32x4 acc[8][4];
#pragma unroll
  for (int i = 0; i < 8; ++i)
#pragma unroll
    for (int j = 0; j < 4; ++j) acc[i][j] = f32x4{0.f, 0.f, 0.f, 0.f};

  const int ar0 = wr * 128;
  const int bc0 = wc * 64;

  // gload staging (A when !CARRY or tile>=16; B always)
  auto stageB = [&](int t) {
    f16* dB = sB + (t & 1) * 16384 + sdst;
    const f16* gB = Bm + (size_t)(n0 + srow) * ldb + t * 64 + scol;
    gload_lds16(gB, dB);
    gload_lds16(gB + (size_t)64 * ldb, dB + 4096);
    gload_lds16(gB + (size_t)128 * ldb, dB + 8192);
    gload_lds16(gB + (size_t)192 * ldb, dB + 12288);
  };
  auto stageA_g = [&](int t) {
    f16* dA = sA + (t & 1) * 16384 + sdst;
    const int kc = CARRY ? (t - 16) * 64 : t * 64;
    const f16* gA = A + (size_t)(m0 + srow) * lda + kc + scol;
    gload_lds16(gA, dA);
    gload_lds16(gA + (size_t)64 * lda, dA + 4096);
    gload_lds16(gA + (size_t)128 * lda, dA + 8192);
    gload_lds16(gA + (size_t)192 * lda, dA + 12288);
  };

  // carry-staged A state (registers; all indices compile-time via unroll)
  uint4 sl[4];
  float2 lpq[4];
  float2 crq[4][4];

  auto cstage_issue = [&](int t) {
    const int nq0 = t * 32 + (scol >> 1);
    const unsigned* sp = sloc_in + (size_t)(m0 + srow) * 512 + nq0;
    const float2* lpp = lamp + (size_t)srow * 512 + nq0;
    const float2* crp = Carry + (size_t)(m0 >> 6) * 512 + nq0;
#pragma unroll
    for (int q = 0; q < 4; ++q) lpq[q] = lpp[q];
#pragma unroll
    for (int i = 0; i < 4; ++i) {
      sl[i] = *(const uint4*)(sp + (size_t)i * 64 * 512);
#pragma unroll
      for (int q = 0; q < 4; ++q) crq[i][q] = crp[(size_t)i * 512 + q];
    }
  };
  auto cstage_finish = [&](int t) {
    f16* dst = sA + (t & 1) * 16384 + tid * 8;
#pragma unroll
    for (int i = 0; i < 4; ++i) {
      unsigned u4[4] = {sl[i].x, sl[i].y, sl[i].z, sl[i].w};
      f16x8 o;
#pragma unroll
      for (int q = 0; q < 4; ++q) {
        f16x2 u = __builtin_bit_cast(f16x2, u4[q]);
        float lx = lpq[q].x, ly = lpq[q].y;
        float cx = crq[i][q].x, cy = crq[i][q].y;
        o[2 * q] = (f16)((float)u.x + lx * cx - ly * cy);
        o[2 * q + 1] = (f16)((float)u.y + lx * cy + ly * cx);
      }
      *(f16x8*)(dst + i * 4096) = o;
    }
  };

  auto stage_issue = [&](int t) {
    stageB(t);
    if (CARRY && t < 16)
      cstage_issue(t);
    else
      stageA_g(t);
  };

  auto barrier = [&]() {
    __builtin_amdgcn_sched_barrier(0);
    __builtin_amdgcn_s_barrier();
    __builtin_amdgcn_sched_barrier(0);
  };

  // prologue
  stage_issue(0);
  if (CARRY) {
    cstage_finish(0);
    asm volatile("s_waitcnt vmcnt(0) lgkmcnt(0)" ::: "memory");
  } else {
    asm volatile("s_waitcnt vmcnt(0)" ::: "memory");
  }
  barrier();

  f16x8 bf[4][2];
  for (int t = 0; t < NT; ++t) {
    const int b = t & 1;
    const f16* bA = sA + b * 16384;
    const f16* bB = sB + b * 16384;
    if (t + 1 < NT) stage_issue(t + 1);
#pragma unroll
    for (int h = 0; h < 4; ++h) {
      if (h == 0) {
#pragma unroll
        for (int nrep = 0; nrep < 4; ++nrep)
#pragma unroll
          for (int ks = 0; ks < 2; ++ks) {
            int row = bc0 + nrep * 16 + fr;
            bf[nrep][ks] =
                *(const f16x8*)(bB + row * 64 + (((ks * 4 + fg) ^ xr) * 8));
          }
      }
      f16x8 af[2][2];
#pragma unroll
      for (int mi = 0; mi < 2; ++mi)
#pragma unroll
        for (int ks = 0; ks < 2; ++ks) {
          int row = ar0 + (h * 2 + mi) * 16 + fr;
          af[mi][ks] =
              *(const f16x8*)(bA + row * 64 + (((ks * 4 + fg) ^ xr) * 8));
        }
      __builtin_amdgcn_s_setprio(1);
#pragma unroll
      for (int mi = 0; mi < 2; ++mi)
#pragma unroll
        for (int nrep = 0; nrep < 4; ++nrep)
#pragma unroll
          for (int ks = 0; ks < 2; ++ks)
            acc[h * 2 + mi][nrep] = __builtin_amdgcn_mfma_f32_16x16x32_f16(
                af[mi][ks], bf[nrep][ks], acc[h * 2 + mi][nrep], 0, 0, 0);
      __builtin_amdgcn_s_setprio(0);
      if (h == 3 && t + 1 < NT) {
        if (CARRY && t + 1 < 16) {
          cstage_finish(t + 1);
          asm volatile("s_waitcnt vmcnt(0) lgkmcnt(0)" ::: "memory");
        } else {
          asm volatile("s_waitcnt vmcnt(0)" ::: "memory");
        }
      }
      barrier();
    }
  }

  if constexpr (FUSE) {
    // ---- fused local scan epilogue (chunk L=64 aligned to wave subtiles) ----
    f16* reg = smem + wid * 8192;
#pragma unroll
    for (int mi = 0; mi < 8; ++mi)
#pragma unroll
      for (int ni = 0; ni < 4; ++ni)
#pragma unroll
        for (int r = 0; r < 4; ++r)
          reg[(mi * 16 + fg * 4 + r) * 64 + ni * 16 + fr] = (f16)acc[mi][ni][r];
    __syncthreads();
    const int half = lane >> 5;
    const int nc = lane & 31;
    const int n = ((n0 + wc * 64) >> 1) + nc;
    const float2 l2 = lam2[n];
    const f16* col = smem + wid * 8192 + (half * 64) * 64 + 2 * nc;
    const int mbase = m0 + wr * 128 + half * 64;
    unsigned* sp = sloc_out + (size_t)mbase * 512 + n;
    float sre = 0.f, sim = 0.f;
#pragma unroll 1
    for (int j0 = 0; j0 < 64; j0 += 8) {
      f16x2 u[8];
#pragma unroll
      for (int q = 0; q < 8; ++q) u[q] = *(const f16x2*)(col + (j0 + q) * 64);
#pragma unroll
      for (int q = 0; q < 8; ++q) {
        float nre = l2.x * sre - l2.y * sim + (float)u[q].x;
        sim = l2.x * sim + l2.y * sre + (float)u[q].y;
        sre = nre;
        f16x2 o;
        o.x = (f16)sre;
        o.y = (f16)sim;
        sp[(size_t)(j0 + q) * 512] = __builtin_bit_cast(unsigned, o);
      }
    }
    Svec[(size_t)((m0 >> 11) * NCHUNK + ((mbase >> 6) & (NCHUNK - 1))) * 512 + n] =
        make_float2(sre, sim);
  } else {
#pragma unroll
    for (int mi = 0; mi < 8; ++mi) {
      int rbase = m0 + ar0 + mi * 16 + fg * 4;
#pragma unroll
      for (int ni = 0; ni < 4; ++ni) {
        int col = n0 + bc0 + ni * 16 + fr;
#pragma unroll
        for (int r = 0; r < 4; ++r)
          C[(size_t)(rbase + r) * ldc + col] = (CT)acc[mi][ni][r];
      }
    }
  }
}

// ---------------- launch ----------------

extern "C" void kernel_launch(void* const* d_in, const int* in_sizes, int n_in,
                              void* d_out, int out_size, void* d_ws, size_t ws_size,
                              hipStream_t stream) {
  const float* input = (const float*)d_in[0];
  const float* Dmat = (const float*)d_in[1];
  const float* nu_log = (const float*)d_in[2];
  const float* theta_log = (const float*)d_in[3];
  const float* gamma_log = (const float*)d_in[4];
  const float* B_re = (const float*)d_in[5];
  const float* B_im = (const float*)d_in[6];
  const float* C_re = (const float*)d_in[7];
  const float* C_im = (const float*)d_in[8];
  float* y = (float*)d_out;

  char* ws = (char*)d_ws;
  size_t off = 0;
  auto alloc = [&](size_t bytes) {
    void* p = ws + off;
    off = (off + bytes + 255) & ~(size_t)255;
    return p;
  };
  float2* lam2 = (float2*)alloc(N_SZ * sizeof(float2));
  float2* lamL2 = (float2*)alloc(N_SZ * sizeof(float2));
  float2* lamp = (float2*)alloc((size_t)LCHUNK * N_SZ * sizeof(float2));  // 256KB
  f16* W1 = (f16*)alloc((size_t)2 * N_SZ * DIN * 2);        // [1024][512] f16
  f16* W2 = (f16*)alloc((size_t)DOUT * 1536 * 2);           // [512][1536] f16
  f16* inp16 = (f16*)alloc((size_t)M_SZ * DIN * 2);         // [M][512] f16
  unsigned* sloc = (unsigned*)alloc((size_t)M_SZ * N_SZ * 4);  // [M][512] f16x2
  float2* S = (float2*)alloc((size_t)B_SZ * NCHUNK * N_SZ * sizeof(float2));
  float2* Carry = (float2*)alloc((size_t)B_SZ * NCHUNK * N_SZ * sizeof(float2));

  const int shmem = 131072;
  {
    auto* g1 = gemm256<f16, true, false>;
    auto* g2 = gemm256<float, false, true>;
    hipFuncSetAttribute((const void*)g1,
                        hipFuncAttributeMaxDynamicSharedMemorySize, shmem);
    hipFuncSetAttribute((const void*)g2,
                        hipFuncAttributeMaxDynamicSharedMemorySize, shmem);
  }

  prep_all<<<13316, 256, 0, stream>>>(nu_log, theta_log, gamma_log, B_re, B_im,
                                      C_re, C_im, Dmat, input, lam2, lamL2, lamp,
                                      W1, W2, inp16);

  // GEMM1 + fused local scan: Bu computed in-register -> sloc, S
  gemm256<f16, true, false><<<512, 512, shmem, stream>>>(
      inp16, 512, W1, 512, (f16*)nullptr, 0, 512, 4, lam2, sloc, S,
      nullptr, nullptr, nullptr);

  scan_b<<<(B_SZ * N_SZ) / 256, 256, 0, stream>>>(S, lamL2, Carry);

  // readout GEMM with in-flight carry application on A K-tiles 0..15
  gemm256<float, false, true><<<256, 512, shmem, stream>>>(
      inp16, 512, W2, 1536, y, 512, 1536, 2, nullptr, nullptr, nullptr,
      sloc, lamp, Carry);
}